// Round 9
// baseline (1553.044 us; speedup 1.0000x reference)
//
#include <hip/hip_runtime.h>
#include <cmath>

#define B_   2048
#define S_   60
#define NTOK (B_*S_)
#define IND_ 211
#define D_   192
#define H_   6
#define DK_  32
#define L_   3
#define DFF_ 768
#define NC_  35
#define DH_  96

typedef unsigned short us_t;
typedef us_t us8 __attribute__((ext_vector_type(8)));
typedef us_t us4 __attribute__((ext_vector_type(4)));
typedef short sh8 __attribute__((ext_vector_type(8)));
typedef float f4 __attribute__((ext_vector_type(4)));
typedef int i4v __attribute__((ext_vector_type(4)));

#define MFMA(a, b, cc) __builtin_amdgcn_mfma_f32_16x16x32_bf16((a), (b), (cc), 0, 0, 0)
#define ZACC(A, M, N) \
    for (int _i = 0; _i < (M); ++_i) \
        for (int _j = 0; _j < (N); ++_j) { \
            A[_i][_j][0] = 0.f; A[_i][_j][1] = 0.f; A[_i][_j][2] = 0.f; A[_i][_j][3] = 0.f; }
#define ZACC1(A, N) \
    for (int _j = 0; _j < (N); ++_j) { \
        A[_j][0] = 0.f; A[_j][1] = 0.f; A[_j][2] = 0.f; A[_j][3] = 0.f; }

__device__ __forceinline__ float bf2f(us_t u) {
    union { unsigned int i; float f; } v; v.i = ((unsigned int)u) << 16; return v.f;
}
__device__ __forceinline__ us_t f2bf(float f) {
    union { float f; unsigned int i; } v; v.f = f;
    unsigned int r = v.i + 0x7fffu + ((v.i >> 16) & 1u);
    return (us_t)(r >> 16);
}
// fast tanh-gelu: |err| < 1e-3 vs exact erf-gelu, well under bf16 rounding
__device__ __forceinline__ float gelu_f(float v) {
    float u = v * (0.7978845608f + 0.0356774081f * v * v);
    float e = __expf(2.f * u);
    float t = 1.f - 2.f / (e + 1.f);       // overflow-safe tanh
    return 0.5f * v * (1.f + t);
}
__device__ __forceinline__ void gld16(const us_t* g, us_t* s) {
    __builtin_amdgcn_global_load_lds(
        (const __attribute__((address_space(1))) unsigned int*)(g),
        (__attribute__((address_space(3))) unsigned int*)(s), 16, 0, 0);
}

// ---------------------------------------------------------------------------
// Weight prep (qkv/wo/inp/clf1): out[n][kp] = bf16(in[kp][n]), zero-pad Kpad.
// ---------------------------------------------------------------------------
__global__ void prep_t(const float* __restrict__ in, us_t* __restrict__ out,
                       int K, int Kpad, int N)
{
    int e = blockIdx.x * 256 + threadIdx.x;
    if (e >= N * Kpad) return;
    int n = e / Kpad, kp = e % Kpad;
    out[e] = (kp < K) ? f2bf(in[(size_t)kp * N + n]) : (us_t)0;
}

// ---------------------------------------------------------------------------
// FF weight prep: 48 K32-subtile images/layer, t = cb*12 + ph*6 + s.
// Image 8192 us_t (16 KB, 16 uniform wave-chunks): [192 rows][40 us_t].
// row = A-operand m (dff col for FF1, out col for FF2), kk = local k.
// ---------------------------------------------------------------------------
__global__ void prep_ff(const float* __restrict__ W1, const float* __restrict__ W2,
                        us_t* __restrict__ WT)
{
    int e = blockIdx.x * 256 + threadIdx.x;
    if (e >= L_ * 48 * 8192) return;
    int l = e / (48 * 8192), r = e % (48 * 8192);
    int t = r / 8192, q = r % 8192;
    int cb = t / 12, p = t % 12, ph = p / 6, s = p % 6;
    us_t v = 0;
    if (q < 7680) {
        int col = q / 40, kk = q % 40;
        if (kk < 32) {
            if (!ph) v = f2bf(W1[((size_t)l * D_ + s * 32 + kk) * DFF_ + cb * 192 + col]);
            else     v = f2bf(W2[((size_t)l * DFF_ + cb * 192 + s * 32 + kk) * D_ + col]);
        }
    }
    WT[e] = v;
}

// ---------------------------------------------------------------------------
// Input projection: h = bf16(x @ W_in + b_in + pe). 64 tok/block, 4 waves.
// ---------------------------------------------------------------------------
__global__ __launch_bounds__(256) void inp_mfma(
    const float* __restrict__ x, const us_t* __restrict__ Wint,
    const float* __restrict__ b_in, const float* __restrict__ pe,
    us_t* __restrict__ h)
{
    __shared__ __align__(16) char smem[29696 + 27648];
    us_t* Xs = (us_t*)smem;              // [64][232]
    us_t* Ws = (us_t*)(smem + 29696);    // [192][72]
    const int tid = threadIdx.x;
    const int lane = tid & 63, wid = tid >> 6;
    const int g = lane >> 4, c = lane & 15;
    const int wr = wid >> 1, wc = wid & 1;
    const int row0 = blockIdx.x * 64;

    for (int e = tid; e < 64 * 224; e += 256) {
        int tok = e / 224, kp = e % 224;
        float v = (kp < IND_) ? x[(size_t)(row0 + tok) * IND_ + kp] : 0.f;
        Xs[tok * 232 + kp] = f2bf(v);
    }

    f4 acc[2][6];
    ZACC(acc, 2, 6);
    for (int pc = 0; pc < 4; ++pc) {
        __syncthreads();
        const int nk = (pc < 3) ? 64 : 32;
        const int per = nk / 8;
        for (int e = tid; e < 192 * per; e += 256) {
            int rw = e / per, v = e % per;
            *(us8*)&Ws[rw * 72 + v * 8] =
                *(const us8*)&Wint[(size_t)rw * 224 + pc * 64 + v * 8];
        }
        __syncthreads();
        for (int kk = 0; kk < nk / 32; ++kk) {
            const int ka = pc * 64 + kk * 32 + g * 8;
            const int kw = kk * 32 + g * 8;
            sh8 a0 = *(const sh8*)&Xs[(32 * wr + c) * 232 + ka];
            sh8 a1 = *(const sh8*)&Xs[(32 * wr + 16 + c) * 232 + ka];
            #pragma unroll
            for (int ni = 0; ni < 6; ++ni) {
                sh8 bf = *(const sh8*)&Ws[(96 * wc + 16 * ni + c) * 72 + kw];
                acc[0][ni] = MFMA(a0, bf, acc[0][ni]);
                acc[1][ni] = MFMA(a1, bf, acc[1][ni]);
            }
        }
    }
    #pragma unroll
    for (int ni = 0; ni < 6; ++ni) {
        const int col = 96 * wc + 16 * ni + c;
        const float bv = b_in[col];
        #pragma unroll
        for (int mi = 0; mi < 2; ++mi)
            #pragma unroll
            for (int r = 0; r < 4; ++r) {
                int tokg = row0 + 32 * wr + 16 * mi + 4 * g + r;
                int s = tokg % S_;
                float val = acc[mi][ni][r] + bv + pe[(size_t)s * D_ + col];
                h[(size_t)tokg * D_ + col] = f2bf(val);
            }
    }
}

// ---------------------------------------------------------------------------
// Fused QKV + attention + Wo + residual + LN. One 512-thread block per batch.
// ---------------------------------------------------------------------------
__global__ __launch_bounds__(512) void qkv_attn_wo(
    us_t* __restrict__ h,
    const us_t* __restrict__ Wqt, const us_t* __restrict__ Wkt,
    const us_t* __restrict__ Wvt, const us_t* __restrict__ Wot,
    const float* __restrict__ bq, const float* __restrict__ bk,
    const float* __restrict__ bv, const float* __restrict__ bo,
    const float* __restrict__ g1, const float* __restrict__ be1)
{
    __shared__ __align__(16) char smem[157696];
    us_t* Xs = (us_t*)smem;               // [64][200]
    us_t* Qs = (us_t*)(smem + 25600);     // [64][200]
    us_t* Ks = (us_t*)(smem + 51200);     // [64][200]
    us_t* Vt = (us_t*)(smem + 76800);     // [192][72] (V transposed)
    us_t* Ws = (us_t*)(smem + 104448);    // [192][72]
    us_t* P0 = (us_t*)(smem + 104448);    // [64][72] overlays Ws
    us_t* P1 = (us_t*)(smem + 113664);    // [64][72]
    us_t* Cx = (us_t*)(smem + 132096);    // [64][200]
    float* eL = (float*)(smem + 51200);   // [64][200] f32 overlays Ks+Vt

    const int tid = threadIdx.x;
    const int lane = tid & 63, wid = tid >> 6;
    const int g = lane >> 4, c = lane & 15;
    const int wr = wid >> 2, wc = wid & 3;
    us_t* hb = h + (size_t)blockIdx.x * (S_ * D_);

    for (int e = tid; e < 1536; e += 512) {
        int tok = e / 24, v = e % 24;
        us8 u = {0, 0, 0, 0, 0, 0, 0, 0};
        if (tok < S_) u = *(const us8*)&hb[(size_t)tok * D_ + v * 8];
        *(us8*)&Xs[tok * 200 + v * 8] = u;
    }

    for (int m = 0; m < 3; ++m) {
        const us_t* Wt = (m == 0) ? Wqt : (m == 1) ? Wkt : Wvt;
        const float* bb = (m == 0) ? bq : (m == 1) ? bk : bv;
        f4 acc[2][3];
        ZACC(acc, 2, 3);
        for (int pc = 0; pc < 3; ++pc) {
            __syncthreads();
            for (int e = tid; e < 1536; e += 512) {
                int rw = e >> 3, v = e & 7;
                *(us8*)&Ws[rw * 72 + v * 8] =
                    *(const us8*)&Wt[(size_t)rw * 192 + pc * 64 + v * 8];
            }
            __syncthreads();
            #pragma unroll
            for (int kk = 0; kk < 2; ++kk) {
                const int ka = pc * 64 + kk * 32 + g * 8;
                const int kw = kk * 32 + g * 8;
                sh8 a0 = *(const sh8*)&Xs[(32 * wr + c) * 200 + ka];
                sh8 a1 = *(const sh8*)&Xs[(32 * wr + 16 + c) * 200 + ka];
                #pragma unroll
                for (int ni = 0; ni < 3; ++ni) {
                    sh8 bf = *(const sh8*)&Ws[(48 * wc + 16 * ni + c) * 72 + kw];
                    acc[0][ni] = MFMA(a0, bf, acc[0][ni]);
                    acc[1][ni] = MFMA(a1, bf, acc[1][ni]);
                }
            }
        }
        #pragma unroll
        for (int ni = 0; ni < 3; ++ni) {
            const int col = 48 * wc + 16 * ni + c;
            const float bval = bb[col];
            #pragma unroll
            for (int mi = 0; mi < 2; ++mi)
                #pragma unroll
                for (int r = 0; r < 4; ++r) {
                    int tok = 32 * wr + 16 * mi + 4 * g + r;
                    us_t o = f2bf(acc[mi][ni][r] + bval);
                    if (m == 0)      Qs[tok * 200 + col] = o;
                    else if (m == 1) Ks[tok * 200 + col] = o;
                    else             Vt[col * 72 + tok] = o;
                }
        }
    }
    __syncthreads();

    const int hgrp = wid & 3;
    const int hsel = wid >> 2;
    for (int rr = 0; rr < 3; ++rr) {
        const int hh = 2 * rr + hsel;
        us_t* Pb = hsel ? P1 : P0;
        f4 sc[4];
        ZACC1(sc, 4);
        {
            const int ka = 32 * hh + g * 8;
            sh8 aq = *(const sh8*)&Qs[(16 * hgrp + c) * 200 + ka];
            #pragma unroll
            for (int ni = 0; ni < 4; ++ni) {
                sh8 bk8 = *(const sh8*)&Ks[(16 * ni + c) * 200 + ka];
                sc[ni] = MFMA(aq, bk8, sc[ni]);
            }
        }
        #pragma unroll
        for (int r = 0; r < 4; ++r) {
            float mx = -1e30f;
            #pragma unroll
            for (int ni = 0; ni < 4; ++ni) {
                float v = sc[ni][r] * 0.17677669529663687f;
                if (16 * ni + c >= S_) v = -1e30f;
                sc[ni][r] = v;
                mx = fmaxf(mx, v);
            }
            mx = fmaxf(mx, __shfl_xor(mx, 1));
            mx = fmaxf(mx, __shfl_xor(mx, 2));
            mx = fmaxf(mx, __shfl_xor(mx, 4));
            mx = fmaxf(mx, __shfl_xor(mx, 8));
            float sum = 0.f;
            #pragma unroll
            for (int ni = 0; ni < 4; ++ni) {
                float e = __expf(sc[ni][r] - mx);
                sc[ni][r] = e; sum += e;
            }
            sum += __shfl_xor(sum, 1);
            sum += __shfl_xor(sum, 2);
            sum += __shfl_xor(sum, 4);
            sum += __shfl_xor(sum, 8);
            const float inv = 1.f / sum;
            #pragma unroll
            for (int ni = 0; ni < 4; ++ni)
                Pb[(16 * hgrp + 4 * g + r) * 72 + 16 * ni + c] = f2bf(sc[ni][r] * inv);
        }
        __syncthreads();
        f4 ov[2];
        ZACC1(ov, 2);
        #pragma unroll
        for (int kk = 0; kk < 2; ++kk) {
            sh8 ap = *(const sh8*)&Pb[(16 * hgrp + c) * 72 + kk * 32 + g * 8];
            #pragma unroll
            for (int n2 = 0; n2 < 2; ++n2) {
                sh8 bv8 = *(const sh8*)&Vt[(32 * hh + 16 * n2 + c) * 72 + kk * 32 + g * 8];
                ov[n2] = MFMA(ap, bv8, ov[n2]);
            }
        }
        #pragma unroll
        for (int n2 = 0; n2 < 2; ++n2)
            #pragma unroll
            for (int r = 0; r < 4; ++r)
                Cx[(16 * hgrp + 4 * g + r) * 200 + 32 * hh + 16 * n2 + c] = f2bf(ov[n2][r]);
        __syncthreads();
    }

    f4 aw[2][3];
    ZACC(aw, 2, 3);
    for (int pc = 0; pc < 3; ++pc) {
        __syncthreads();
        for (int e = tid; e < 1536; e += 512) {
            int rw = e >> 3, v = e & 7;
            *(us8*)&Ws[rw * 72 + v * 8] =
                *(const us8*)&Wot[(size_t)rw * 192 + pc * 64 + v * 8];
        }
        __syncthreads();
        #pragma unroll
        for (int kk = 0; kk < 2; ++kk) {
            const int ka = pc * 64 + kk * 32 + g * 8;
            const int kw = kk * 32 + g * 8;
            sh8 a0 = *(const sh8*)&Cx[(32 * wr + c) * 200 + ka];
            sh8 a1 = *(const sh8*)&Cx[(32 * wr + 16 + c) * 200 + ka];
            #pragma unroll
            for (int ni = 0; ni < 3; ++ni) {
                sh8 bf = *(const sh8*)&Ws[(48 * wc + 16 * ni + c) * 72 + kw];
                aw[0][ni] = MFMA(a0, bf, aw[0][ni]);
                aw[1][ni] = MFMA(a1, bf, aw[1][ni]);
            }
        }
    }
    __syncthreads();
    #pragma unroll
    for (int ni = 0; ni < 3; ++ni) {
        const int col = 48 * wc + 16 * ni + c;
        const float bov = bo[col];
        #pragma unroll
        for (int mi = 0; mi < 2; ++mi)
            #pragma unroll
            for (int r = 0; r < 4; ++r) {
                int tok = 32 * wr + 16 * mi + 4 * g + r;
                eL[tok * 200 + col] = aw[mi][ni][r] + bov + bf2f(Xs[tok * 200 + col]);
            }
    }
    __syncthreads();
    {
        const int tok = tid >> 3, t8 = tid & 7;
        float vals[24], sum = 0.f, ssq = 0.f;
        #pragma unroll
        for (int jv = 0; jv < 6; ++jv) {
            float4 v4 = *(const float4*)&eL[tok * 200 + t8 * 24 + jv * 4];
            vals[jv*4+0] = v4.x; vals[jv*4+1] = v4.y; vals[jv*4+2] = v4.z; vals[jv*4+3] = v4.w;
            sum += v4.x + v4.y + v4.z + v4.w;
            ssq += v4.x*v4.x + v4.y*v4.y + v4.z*v4.z + v4.w*v4.w;
        }
        sum += __shfl_xor(sum, 1); sum += __shfl_xor(sum, 2); sum += __shfl_xor(sum, 4);
        ssq += __shfl_xor(ssq, 1); ssq += __shfl_xor(ssq, 2); ssq += __shfl_xor(ssq, 4);
        const float mean = sum * (1.f / D_);
        const float var  = ssq * (1.f / D_) - mean * mean;
        const float rstd = rsqrtf(var + 1e-5f);
        if (tok < S_) {
            #pragma unroll
            for (int jv = 0; jv < 6; ++jv) {
                us4 o4;
                #pragma unroll
                for (int j = 0; j < 4; ++j) {
                    int col = t8 * 24 + jv * 4 + j;
                    o4[j] = f2bf((vals[jv*4+j] - mean) * rstd * g1[col] + be1[col]);
                }
                *(us4*)&hb[(size_t)tok * D_ + t8 * 24 + jv * 4] = o4;
            }
        }
    }
}

// ---------------------------------------------------------------------------
// Fused FF, wave-owns-full-rows: M=128, 8 waves x 16 tokens, ni=12 (full 192
// cols per cb). X in VGPRs; FF1->FF2 intermediate redistributed in-register
// via shfl_xor(16/32/48) -- no Xs/Ts LDS at all. LDS = tri-buffered W tiles
// (48 KB) with counted vmcnt(2); raw s_barrier only for W staging.
// ---------------------------------------------------------------------------
__global__ __launch_bounds__(512) void ff_mfma(
    us_t* __restrict__ hio,
    const us_t* __restrict__ WT, const float* __restrict__ b1,
    const float* __restrict__ b2,
    const float* __restrict__ gamma, const float* __restrict__ beta)
{
    __shared__ __align__(16) us_t Wsb[3][8192];   // 48 KB

    const int tid = threadIdx.x;
    const int lane = tid & 63, wid = tid >> 6;
    const int g = lane >> 4, c = lane & 15;
    const int row0 = blockIdx.x * 128;
    const int trow = row0 + 16 * wid + c;          // this lane's token row

    // stage tile -> slot: 16 chunks of 1 KB, exactly 2 per wave (uniform)
    auto stage = [&](int t, int slot) {
        const us_t* src = WT + (size_t)t * 8192;
        us_t* dst = &Wsb[slot][0];
        #pragma unroll
        for (int i = 0; i < 2; ++i)
            gld16(src + (wid * 2 + i) * 512 + lane * 8, dst + (wid * 2 + i) * 512);
    };

    // prologue: stage tiles 0,1; preload X fragments (B-operand layout)
    stage(0, 0);
    stage(1, 1);
    sh8 Xf[6];
    {
        const us_t* hr = hio + (size_t)trow * D_;
        #pragma unroll
        for (int s = 0; s < 6; ++s)
            Xf[s] = *(const sh8*)&hr[32 * s + 8 * g];
    }
    asm volatile("s_waitcnt vmcnt(2)" ::: "memory");
    __builtin_amdgcn_s_barrier();

    f4 acc1[12], acc2[12];
    ZACC1(acc2, 12);
    unsigned tp[12][2];

    for (int cb = 0; cb < 4; ++cb) {
        ZACC1(acc1, 12);
        #pragma unroll
        for (int p = 0; p < 12; ++p) {
            const int t = cb * 12 + p;
            const int s = p % 6;
            const bool isff1 = (p < 6);
            const bool dostage = (t + 2 < 48);
            if (dostage) stage(t + 2, (p + 2) % 3);
            const us_t* W = &Wsb[p % 3][0];

            if (isff1) {
                #pragma unroll
                for (int ni = 0; ni < 12; ++ni) {
                    sh8 wa = *(const sh8*)&W[(16 * ni + c) * 40 + 8 * g];
                    acc1[ni] = MFMA(wa, Xf[s], acc1[ni]);
                }
            } else {
                // build T fragment for K-window s (in-register redistribution)
                unsigned P0 = tp[2 * s + (g >> 1)][0];
                unsigned P1 = tp[2 * s + (g >> 1)][1];
                unsigned Q0 = tp[2 * s + ((g >> 1) ^ 1)][0];
                unsigned Q1 = tp[2 * s + ((g >> 1) ^ 1)][1];
                unsigned r16_0 = (unsigned)__shfl_xor((int)P0, 16);
                unsigned r16_1 = (unsigned)__shfl_xor((int)P1, 16);
                unsigned r32_0 = (unsigned)__shfl_xor((int)Q0, 32);
                unsigned r32_1 = (unsigned)__shfl_xor((int)Q1, 32);
                unsigned r48_0 = (unsigned)__shfl_xor((int)Q0, 48);
                unsigned r48_1 = (unsigned)__shfl_xor((int)Q1, 48);
                unsigned a0, a1, d0, d1;
                if (g == 0)      { a0 = P0;    a1 = P1;    d0 = r16_0; d1 = r16_1; }
                else if (g == 1) { a0 = r48_0; a1 = r48_1; d0 = r32_0; d1 = r32_1; }
                else if (g == 2) { a0 = r32_0; a1 = r32_1; d0 = r48_0; d1 = r48_1; }
                else             { a0 = r16_0; a1 = r16_1; d0 = P0;    d1 = P1;    }
                union { i4v u; sh8 s8; } cvt;
                cvt.u[0] = (int)a0; cvt.u[1] = (int)a1; cvt.u[2] = (int)d0; cvt.u[3] = (int)d1;
                sh8 Tf = cvt.s8;
                #pragma unroll
                for (int ni = 0; ni < 12; ++ni) {
                    sh8 wa = *(const sh8*)&W[(16 * ni + c) * 40 + 8 * g];
                    acc2[ni] = MFMA(wa, Tf, acc2[ni]);
                }
            }

            if (isff1 && s == 5) {
                // FF1 done for this cb: bias + gelu + pack to bf16 pairs
                #pragma unroll
                for (int ni = 0; ni < 12; ++ni) {
                    float4 bv = *(const float4*)&b1[cb * 192 + 16 * ni + 4 * g];
                    float t0 = gelu_f(acc1[ni][0] + bv.x);
                    float t1 = gelu_f(acc1[ni][1] + bv.y);
                    float t2 = gelu_f(acc1[ni][2] + bv.z);
                    float t3 = gelu_f(acc1[ni][3] + bv.w);
                    tp[ni][0] = (unsigned)f2bf(t0) | ((unsigned)f2bf(t1) << 16);
                    tp[ni][1] = (unsigned)f2bf(t2) | ((unsigned)f2bf(t3) << 16);
                }
                asm volatile("s_waitcnt vmcnt(0)" ::: "memory");
            } else if (dostage) {
                asm volatile("s_waitcnt vmcnt(2)" ::: "memory");
            } else {
                asm volatile("s_waitcnt vmcnt(0)" ::: "memory");
            }
            __builtin_amdgcn_s_barrier();
        }
    }

    // epilogue: acc2[ni][r] = OUT[outcol=16ni+4g+r][tok=trow]; no barriers
    const us_t* hr = hio + (size_t)trow * D_;
    float vv[12][4];
    float sum = 0.f, ssq = 0.f;
    #pragma unroll
    for (int ni = 0; ni < 12; ++ni) {
        const int d0 = 16 * ni + 4 * g;
        float4 b2v = *(const float4*)&b2[d0];
        us4 rv = *(const us4*)&hr[d0];
        #pragma unroll
        for (int r = 0; r < 4; ++r) {
            float val = acc2[ni][r] + ((const float*)&b2v)[r] + bf2f(rv[r]);
            vv[ni][r] = val; sum += val; ssq += val * val;
        }
    }
    sum += __shfl_xor(sum, 16); sum += __shfl_xor(sum, 32);
    ssq += __shfl_xor(ssq, 16); ssq += __shfl_xor(ssq, 32);
    const float mean = sum * (1.f / D_);
    const float var  = ssq * (1.f / D_) - mean * mean;
    const float rstd = rsqrtf(var + 1e-5f);
    us_t* orow = hio + (size_t)trow * D_;
    #pragma unroll
    for (int ni = 0; ni < 12; ++ni) {
        const int d0 = 16 * ni + 4 * g;
        float4 gv  = *(const float4*)&gamma[d0];
        float4 bev = *(const float4*)&beta[d0];
        us4 o4;
        o4[0] = f2bf((vv[ni][0] - mean) * rstd * gv.x + bev.x);
        o4[1] = f2bf((vv[ni][1] - mean) * rstd * gv.y + bev.y);
        o4[2] = f2bf((vv[ni][2] - mean) * rstd * gv.z + bev.z);
        o4[3] = f2bf((vv[ni][3] - mean) * rstd * gv.w + bev.w);
        *(us4*)&orow[d0] = o4;
    }
}

// ---------------------------------------------------------------------------
// Classifier stage 1 (MFMA): hid = bf16(gelu(h @ Wc1 + bc1)). 64 tok/block.
// ---------------------------------------------------------------------------
__global__ __launch_bounds__(256) void clf1_mfma(
    const us_t* __restrict__ h, const us_t* __restrict__ Wc1t,
    const float* __restrict__ bc1, us_t* __restrict__ hid)
{
    __shared__ __align__(16) char smem[25600 + 13824];
    us_t* Xs = (us_t*)smem;              // [64][200]
    us_t* Ws = (us_t*)(smem + 25600);    // [96][72]
    const int tid = threadIdx.x;
    const int lane = tid & 63, wid = tid >> 6;
    const int g = lane >> 4, c = lane & 15;
    const int wr = wid >> 1, wc = wid & 1;
    const int row0 = blockIdx.x * 64;

    for (int e = tid; e < 1536; e += 256) {
        int tok = e / 24, v = e % 24;
        *(us8*)&Xs[tok * 200 + v * 8] = *(const us8*)&h[(size_t)(row0 + tok) * D_ + v * 8];
    }
    f4 acc[2][3];
    ZACC(acc, 2, 3);
    for (int pc = 0; pc < 3; ++pc) {
        __syncthreads();
        for (int e = tid; e < 768; e += 256) {
            int rw = e >> 3, v = e & 7;
            *(us8*)&Ws[rw * 72 + v * 8] =
                *(const us8*)&Wc1t[(size_t)rw * 192 + pc * 64 + v * 8];
        }
        __syncthreads();
        #pragma unroll
        for (int kk = 0; kk < 2; ++kk) {
            const int ka = pc * 64 + kk * 32 + g * 8;
            const int kw = kk * 32 + g * 8;
            sh8 a0 = *(const sh8*)&Xs[(32 * wr + c) * 200 + ka];
            sh8 a1 = *(const sh8*)&Xs[(32 * wr + 16 + c) * 200 + ka];
            #pragma unroll
            for (int ni = 0; ni < 3; ++ni) {
                sh8 bf = *(const sh8*)&Ws[(48 * wc + 16 * ni + c) * 72 + kw];
                acc[0][ni] = MFMA(a0, bf, acc[0][ni]);
                acc[1][ni] = MFMA(a1, bf, acc[1][ni]);
            }
        }
    }
    #pragma unroll
    for (int ni = 0; ni < 3; ++ni) {
        const int col = 48 * wc + 16 * ni + c;
        const float bv = bc1[col];
        #pragma unroll
        for (int mi = 0; mi < 2; ++mi)
            #pragma unroll
            for (int r = 0; r < 4; ++r) {
                int tok = row0 + 32 * wr + 16 * mi + 4 * g + r;
                hid[(size_t)tok * DH_ + col] = f2bf(gelu_f(acc[mi][ni][r] + bv));
            }
    }
}

// ---------------------------------------------------------------------------
// Classifier stage 2: out = hid @ Wc2 + bc2 (f32 VALU, tiny)
// ---------------------------------------------------------------------------
__global__ __launch_bounds__(256) void clf2_kernel(
    const us_t* __restrict__ hid, const float* __restrict__ Wc2,
    const float* __restrict__ bc2, float* __restrict__ out)
{
    __shared__ us_t Hs[64 * 104];
    __shared__ float Wl[DH_ * NC_];
    __shared__ float bl[NC_];
    const int tid = threadIdx.x;
    const int row0 = blockIdx.x * 64;
    for (int e = tid; e < 768; e += 256) {
        int tok = e / 12, v = e % 12;
        *(us8*)&Hs[tok * 104 + v * 8] = *(const us8*)&hid[(size_t)(row0 + tok) * DH_ + v * 8];
    }
    for (int e = tid; e < DH_ * NC_; e += 256) Wl[e] = Wc2[e];
    if (tid < NC_) bl[tid] = bc2[tid];
    __syncthreads();
    for (int e = tid; e < 64 * NC_; e += 256) {
        const int tok = e / NC_, col = e % NC_;
        float acc = bl[col];
        #pragma unroll 8
        for (int kk = 0; kk < DH_; ++kk)
            acc = fmaf(bf2f(Hs[tok * 104 + kk]), Wl[kk * NC_ + col], acc);
        out[(size_t)(row0 + tok) * NC_ + col] = acc;
    }
}

extern "C" void kernel_launch(void* const* d_in, const int* in_sizes, int n_in,
                              void* d_out, int out_size, void* d_ws, size_t ws_size,
                              hipStream_t stream)
{
    const float* x    = (const float*)d_in[0];
    const float* W_in = (const float*)d_in[1];
    const float* b_in = (const float*)d_in[2];
    const float* pe   = (const float*)d_in[3];
    const float* Wq   = (const float*)d_in[4];
    const float* bq   = (const float*)d_in[5];
    const float* Wk   = (const float*)d_in[6];
    const float* bk   = (const float*)d_in[7];
    const float* Wv   = (const float*)d_in[8];
    const float* bv   = (const float*)d_in[9];
    const float* Wo   = (const float*)d_in[10];
    const float* bo   = (const float*)d_in[11];
    const float* W1   = (const float*)d_in[12];
    const float* b1   = (const float*)d_in[13];
    const float* W2   = (const float*)d_in[14];
    const float* b2   = (const float*)d_in[15];
    const float* g1   = (const float*)d_in[16];
    const float* be1  = (const float*)d_in[17];
    const float* g2   = (const float*)d_in[18];
    const float* be2  = (const float*)d_in[19];
    const float* Wc1  = (const float*)d_in[20];
    const float* bc1  = (const float*)d_in[21];
    const float* Wc2  = (const float*)d_in[22];
    const float* bc2  = (const float*)d_in[23];
    float* outp = (float*)d_out;

    // ws layout (us_t elems): h | hid | Wint | Wq/k/v/ot | WT(ff) | Wc1t
    us_t* h    = (us_t*)d_ws;
    us_t* hid  = h + (size_t)NTOK * D_;
    us_t* Wint = hid + (size_t)NTOK * DH_;
    us_t* Wqt  = Wint + 192 * 224;
    us_t* Wkt  = Wqt + 3 * 36864;
    us_t* Wvt  = Wkt + 3 * 36864;
    us_t* Wot  = Wvt + 3 * 36864;
    us_t* WT   = Wot + 3 * 36864;
    us_t* Wc1t = WT + (size_t)L_ * 48 * 8192;

    // ---- weight prep ----
    prep_t<<<168, 256, 0, stream>>>(W_in, Wint, IND_, 224, D_);
    for (int l = 0; l < L_; ++l) {
        prep_t<<<144, 256, 0, stream>>>(Wq + (size_t)l * 36864, Wqt + (size_t)l * 36864, 192, 192, 192);
        prep_t<<<144, 256, 0, stream>>>(Wk + (size_t)l * 36864, Wkt + (size_t)l * 36864, 192, 192, 192);
        prep_t<<<144, 256, 0, stream>>>(Wv + (size_t)l * 36864, Wvt + (size_t)l * 36864, 192, 192, 192);
        prep_t<<<144, 256, 0, stream>>>(Wo + (size_t)l * 36864, Wot + (size_t)l * 36864, 192, 192, 192);
    }
    prep_ff<<<(L_ * 48 * 8192 + 255) / 256, 256, 0, stream>>>(W1, W2, WT);
    prep_t<<<72, 256, 0, stream>>>(Wc1, Wc1t, 192, 192, DH_);

    // ---- forward ----
    inp_mfma<<<NTOK / 64, 256, 0, stream>>>(x, Wint, b_in, pe, h);

    for (int l = 0; l < L_; ++l) {
        qkv_attn_wo<<<B_, 512, 0, stream>>>(
            h,
            Wqt + (size_t)l * 36864, Wkt + (size_t)l * 36864,
            Wvt + (size_t)l * 36864, Wot + (size_t)l * 36864,
            bq + l * D_, bk + l * D_, bv + l * D_, bo + l * D_,
            g1 + l * D_, be1 + l * D_);
        ff_mfma<<<NTOK / 128, 512, 0, stream>>>(
            h, WT + (size_t)l * 48 * 8192, b1 + l * DFF_, b2 + l * D_,
            g2 + l * D_, be2 + l * D_);
    }

    clf1_mfma<<<NTOK / 64, 256, 0, stream>>>(h, Wc1t, bc1, hid);
    clf2_kernel<<<NTOK / 64, 256, 0, stream>>>(hid, Wc2, bc2, outp);
}

// Round 11
// 1179.901 us; speedup vs baseline: 1.3162x; 1.3162x over previous
//
#include <hip/hip_runtime.h>
#include <cmath>

#define B_   2048
#define S_   60
#define NTOK (B_*S_)
#define IND_ 211
#define D_   192
#define H_   6
#define DK_  32
#define L_   3
#define DFF_ 768
#define NC_  35
#define DH_  96

typedef unsigned short us_t;
typedef us_t us8 __attribute__((ext_vector_type(8)));
typedef us_t us4 __attribute__((ext_vector_type(4)));
typedef short sh8 __attribute__((ext_vector_type(8)));
typedef float f4 __attribute__((ext_vector_type(4)));

#define MFMA(a, b, cc) __builtin_amdgcn_mfma_f32_16x16x32_bf16((a), (b), (cc), 0, 0, 0)
#define ZACC(A, M, N) \
    for (int _i = 0; _i < (M); ++_i) \
        for (int _j = 0; _j < (N); ++_j) { \
            A[_i][_j][0] = 0.f; A[_i][_j][1] = 0.f; A[_i][_j][2] = 0.f; A[_i][_j][3] = 0.f; }
#define ZACC1(A, N) \
    for (int _j = 0; _j < (N); ++_j) { \
        A[_j][0] = 0.f; A[_j][1] = 0.f; A[_j][2] = 0.f; A[_j][3] = 0.f; }

__device__ __forceinline__ float bf2f(us_t u) {
    union { unsigned int i; float f; } v; v.i = ((unsigned int)u) << 16; return v.f;
}
__device__ __forceinline__ us_t f2bf(float f) {
    union { float f; unsigned int i; } v; v.f = f;
    unsigned int r = v.i + 0x7fffu + ((v.i >> 16) & 1u);
    return (us_t)(r >> 16);
}
// fast tanh-gelu: |err| < 1e-3 vs exact erf-gelu, well under bf16 rounding
__device__ __forceinline__ float gelu_f(float v) {
    float u = v * (0.7978845608f + 0.0356774081f * v * v);
    float e = __expf(2.f * u);
    float t = 1.f - 2.f / (e + 1.f);       // overflow-safe tanh
    return 0.5f * v * (1.f + t);
}
__device__ __forceinline__ void gld16(const us_t* g, us_t* s) {
    __builtin_amdgcn_global_load_lds(
        (const __attribute__((address_space(1))) unsigned int*)(g),
        (__attribute__((address_space(3))) unsigned int*)(s), 16, 0, 0);
}

// ---------------------------------------------------------------------------
// Weight prep (qkv/wo/inp/clf1): out[n][kp] = bf16(in[kp][n]), zero-pad Kpad.
// ---------------------------------------------------------------------------
__global__ void prep_t(const float* __restrict__ in, us_t* __restrict__ out,
                       int K, int Kpad, int N)
{
    int e = blockIdx.x * 256 + threadIdx.x;
    if (e >= N * Kpad) return;
    int n = e / Kpad, kp = e % Kpad;
    out[e] = (kp < K) ? f2bf(in[(size_t)kp * N + n]) : (us_t)0;
}

// ---------------------------------------------------------------------------
// FF weight prep: tile-contiguous LDS images. Per layer 12 tiles x [192][72].
// ---------------------------------------------------------------------------
__global__ void prep_ff(const float* __restrict__ W1, const float* __restrict__ W2,
                        us_t* __restrict__ W1T, us_t* __restrict__ W2T)
{
    int e = blockIdx.x * 256 + threadIdx.x;
    if (e >= L_ * 12 * 13824) return;
    int l = e / (12 * 13824), r = e % (12 * 13824);
    int tile = r / 13824, q = r % 13824;
    int col = q / 72, kk = q % 72;
    int cb = tile / 3, pc = tile % 3;
    us_t v1 = 0, v2 = 0;
    if (kk < 64) {
        v1 = f2bf(W1[((size_t)l * D_ + pc * 64 + kk) * DFF_ + cb * D_ + col]);
        v2 = f2bf(W2[((size_t)l * DFF_ + cb * D_ + pc * 64 + kk) * D_ + col]);
    }
    W1T[e] = v1; W2T[e] = v2;
}

// ---------------------------------------------------------------------------
// Input projection: h = bf16(x @ W_in + b_in + pe). 64 tok/block, 4 waves.
// ---------------------------------------------------------------------------
__global__ __launch_bounds__(256) void inp_mfma(
    const float* __restrict__ x, const us_t* __restrict__ Wint,
    const float* __restrict__ b_in, const float* __restrict__ pe,
    us_t* __restrict__ h)
{
    __shared__ __align__(16) char smem[29696 + 27648];
    us_t* Xs = (us_t*)smem;              // [64][232]
    us_t* Ws = (us_t*)(smem + 29696);    // [192][72]
    const int tid = threadIdx.x;
    const int lane = tid & 63, wid = tid >> 6;
    const int g = lane >> 4, c = lane & 15;
    const int wr = wid >> 1, wc = wid & 1;
    const int row0 = blockIdx.x * 64;

    for (int e = tid; e < 64 * 224; e += 256) {
        int tok = e / 224, kp = e % 224;
        float v = (kp < IND_) ? x[(size_t)(row0 + tok) * IND_ + kp] : 0.f;
        Xs[tok * 232 + kp] = f2bf(v);
    }

    f4 acc[2][6];
    ZACC(acc, 2, 6);
    for (int pc = 0; pc < 4; ++pc) {
        __syncthreads();
        const int nk = (pc < 3) ? 64 : 32;
        const int per = nk / 8;
        for (int e = tid; e < 192 * per; e += 256) {
            int rw = e / per, v = e % per;
            *(us8*)&Ws[rw * 72 + v * 8] =
                *(const us8*)&Wint[(size_t)rw * 224 + pc * 64 + v * 8];
        }
        __syncthreads();
        for (int kk = 0; kk < nk / 32; ++kk) {
            const int ka = pc * 64 + kk * 32 + g * 8;
            const int kw = kk * 32 + g * 8;
            sh8 a0 = *(const sh8*)&Xs[(32 * wr + c) * 232 + ka];
            sh8 a1 = *(const sh8*)&Xs[(32 * wr + 16 + c) * 232 + ka];
            #pragma unroll
            for (int ni = 0; ni < 6; ++ni) {
                sh8 bf = *(const sh8*)&Ws[(96 * wc + 16 * ni + c) * 72 + kw];
                acc[0][ni] = MFMA(a0, bf, acc[0][ni]);
                acc[1][ni] = MFMA(a1, bf, acc[1][ni]);
            }
        }
    }
    #pragma unroll
    for (int ni = 0; ni < 6; ++ni) {
        const int col = 96 * wc + 16 * ni + c;
        const float bv = b_in[col];
        #pragma unroll
        for (int mi = 0; mi < 2; ++mi)
            #pragma unroll
            for (int r = 0; r < 4; ++r) {
                int tokg = row0 + 32 * wr + 16 * mi + 4 * g + r;
                int s = tokg % S_;
                float val = acc[mi][ni][r] + bv + pe[(size_t)s * D_ + col];
                h[(size_t)tokg * D_ + col] = f2bf(val);
            }
    }
}

// ---------------------------------------------------------------------------
// Fused QKV + attention + Wo + residual + LN. 1024 threads (16 waves,
// 4 waves/SIMD). Attention: 2 rounds x 3 concurrent heads (12 active waves),
// P[3] slots overlay the Ws staging region.
// ---------------------------------------------------------------------------
__global__ __launch_bounds__(1024) void qkv_attn_wo(
    us_t* __restrict__ h,
    const us_t* __restrict__ Wqt, const us_t* __restrict__ Wkt,
    const us_t* __restrict__ Wvt, const us_t* __restrict__ Wot,
    const float* __restrict__ bq, const float* __restrict__ bk,
    const float* __restrict__ bv, const float* __restrict__ bo,
    const float* __restrict__ g1, const float* __restrict__ be1)
{
    __shared__ __align__(16) char smem[157696];
    us_t* Xs  = (us_t*)smem;               // [64][200]  25600
    us_t* Qs  = (us_t*)(smem + 25600);     // [64][200]
    us_t* Ks  = (us_t*)(smem + 51200);     // [64][200]
    us_t* Vt  = (us_t*)(smem + 76800);     // [192][72] (V transposed)
    us_t* Ws  = (us_t*)(smem + 104448);    // [192][72] proj/Wo staging
    us_t* Pb3 = (us_t*)(smem + 104448);    // [3][64][72] attn P, overlays Ws
    us_t* Cx  = (us_t*)(smem + 132096);    // [64][200]
    float* eL = (float*)(smem + 51200);    // [64][200] f32, overlays Ks+Vt

    const int tid = threadIdx.x;
    const int lane = tid & 63, wid = tid >> 6;   // 16 waves
    const int g = lane >> 4, c = lane & 15;
    const int wr = wid >> 2, wc = wid & 3;       // 4x16-row, 4x48-col
    us_t* hb = h + (size_t)blockIdx.x * (S_ * D_);

    // stage X (rows 60..63 zero)
    for (int e = tid; e < 1536; e += 1024) {
        int tok = e / 24, v = e % 24;
        us8 u = {0, 0, 0, 0, 0, 0, 0, 0};
        if (tok < S_) u = *(const us8*)&hb[(size_t)tok * D_ + v * 8];
        *(us8*)&Xs[tok * 200 + v * 8] = u;
    }

    // ---- QKV projections ----
    for (int m = 0; m < 3; ++m) {
        const us_t* Wt = (m == 0) ? Wqt : (m == 1) ? Wkt : Wvt;
        const float* bb = (m == 0) ? bq : (m == 1) ? bk : bv;
        f4 acc[3];
        ZACC1(acc, 3);
        for (int pc = 0; pc < 3; ++pc) {
            __syncthreads();
            for (int e = tid; e < 1536; e += 1024) {
                int rw = e >> 3, v = e & 7;
                *(us8*)&Ws[rw * 72 + v * 8] =
                    *(const us8*)&Wt[(size_t)rw * 192 + pc * 64 + v * 8];
            }
            __syncthreads();
            #pragma unroll
            for (int kk = 0; kk < 2; ++kk) {
                const int ka = pc * 64 + kk * 32 + g * 8;
                const int kw = kk * 32 + g * 8;
                sh8 a0 = *(const sh8*)&Xs[(16 * wr + c) * 200 + ka];
                #pragma unroll
                for (int ni = 0; ni < 3; ++ni) {
                    sh8 bf = *(const sh8*)&Ws[(48 * wc + 16 * ni + c) * 72 + kw];
                    acc[ni] = MFMA(a0, bf, acc[ni]);
                }
            }
        }
        #pragma unroll
        for (int ni = 0; ni < 3; ++ni) {
            const int col = 48 * wc + 16 * ni + c;
            const float bval = bb[col];
            #pragma unroll
            for (int r = 0; r < 4; ++r) {
                int tok = 16 * wr + 4 * g + r;
                us_t o = f2bf(acc[ni][r] + bval);
                if (m == 0)      Qs[tok * 200 + col] = o;
                else if (m == 1) Ks[tok * 200 + col] = o;
                else             Vt[col * 72 + tok] = o;
            }
        }
    }
    __syncthreads();

    // ---- attention: 2 rounds x 3 heads; 12 active waves per round ----
    for (int rr2 = 0; rr2 < 2; ++rr2) {
        const bool act = (wid < 12);
        const int hh = 3 * rr2 + (wid >> 2);   // head (valid when act)
        const int hgrp = wid & 3;              // q row-block
        us_t* Pb = Pb3 + (size_t)(wid >> 2) * 4608;   // 64*72
        if (act) {
            f4 sc[4];
            ZACC1(sc, 4);
            const int ka = 32 * hh + g * 8;
            sh8 aq = *(const sh8*)&Qs[(16 * hgrp + c) * 200 + ka];
            #pragma unroll
            for (int ni = 0; ni < 4; ++ni) {
                sh8 bk8 = *(const sh8*)&Ks[(16 * ni + c) * 200 + ka];
                sc[ni] = MFMA(aq, bk8, sc[ni]);
            }
            #pragma unroll
            for (int r = 0; r < 4; ++r) {
                float mx = -1e30f;
                #pragma unroll
                for (int ni = 0; ni < 4; ++ni) {
                    float v = sc[ni][r] * 0.17677669529663687f;
                    if (16 * ni + c >= S_) v = -1e30f;
                    sc[ni][r] = v;
                    mx = fmaxf(mx, v);
                }
                mx = fmaxf(mx, __shfl_xor(mx, 1));
                mx = fmaxf(mx, __shfl_xor(mx, 2));
                mx = fmaxf(mx, __shfl_xor(mx, 4));
                mx = fmaxf(mx, __shfl_xor(mx, 8));
                float sum = 0.f;
                #pragma unroll
                for (int ni = 0; ni < 4; ++ni) {
                    float e = __expf(sc[ni][r] - mx);
                    sc[ni][r] = e; sum += e;
                }
                sum += __shfl_xor(sum, 1);
                sum += __shfl_xor(sum, 2);
                sum += __shfl_xor(sum, 4);
                sum += __shfl_xor(sum, 8);
                const float inv = 1.f / sum;
                #pragma unroll
                for (int ni = 0; ni < 4; ++ni)
                    Pb[(16 * hgrp + 4 * g + r) * 72 + 16 * ni + c] = f2bf(sc[ni][r] * inv);
            }
        }
        __syncthreads();
        if (act) {
            f4 ov[2];
            ZACC1(ov, 2);
            #pragma unroll
            for (int kk = 0; kk < 2; ++kk) {
                sh8 ap = *(const sh8*)&Pb[(16 * hgrp + c) * 72 + kk * 32 + g * 8];
                #pragma unroll
                for (int n2 = 0; n2 < 2; ++n2) {
                    sh8 bv8 = *(const sh8*)&Vt[(32 * hh + 16 * n2 + c) * 72 + kk * 32 + g * 8];
                    ov[n2] = MFMA(ap, bv8, ov[n2]);
                }
            }
            #pragma unroll
            for (int n2 = 0; n2 < 2; ++n2)
                #pragma unroll
                for (int r = 0; r < 4; ++r)
                    Cx[(16 * hgrp + 4 * g + r) * 200 + 32 * hh + 16 * n2 + c] = f2bf(ov[n2][r]);
        }
        __syncthreads();
    }

    // ---- Wo projection ----
    f4 aw[3];
    ZACC1(aw, 3);
    for (int pc = 0; pc < 3; ++pc) {
        __syncthreads();
        for (int e = tid; e < 1536; e += 1024) {
            int rw = e >> 3, v = e & 7;
            *(us8*)&Ws[rw * 72 + v * 8] =
                *(const us8*)&Wot[(size_t)rw * 192 + pc * 64 + v * 8];
        }
        __syncthreads();
        #pragma unroll
        for (int kk = 0; kk < 2; ++kk) {
            const int ka = pc * 64 + kk * 32 + g * 8;
            const int kw = kk * 32 + g * 8;
            sh8 a0 = *(const sh8*)&Cx[(16 * wr + c) * 200 + ka];
            #pragma unroll
            for (int ni = 0; ni < 3; ++ni) {
                sh8 bf = *(const sh8*)&Ws[(48 * wc + 16 * ni + c) * 72 + kw];
                aw[ni] = MFMA(a0, bf, aw[ni]);
            }
        }
    }
    __syncthreads();
    // residual add into eL
    #pragma unroll
    for (int ni = 0; ni < 3; ++ni) {
        const int col = 48 * wc + 16 * ni + c;
        const float bov = bo[col];
        #pragma unroll
        for (int r = 0; r < 4; ++r) {
            int tok = 16 * wr + 4 * g + r;
            eL[tok * 200 + col] = aw[ni][r] + bov + bf2f(Xs[tok * 200 + col]);
        }
    }
    __syncthreads();
    // LayerNorm: 64 rows x 16 lanes, 12 cols each
    {
        const int tl = tid >> 4, t16 = tid & 15;
        float vals[12], sum = 0.f, ssq = 0.f;
        #pragma unroll
        for (int jv = 0; jv < 3; ++jv) {
            float4 v4 = *(const float4*)&eL[tl * 200 + t16 * 12 + jv * 4];
            vals[jv*4+0] = v4.x; vals[jv*4+1] = v4.y; vals[jv*4+2] = v4.z; vals[jv*4+3] = v4.w;
            sum += v4.x + v4.y + v4.z + v4.w;
            ssq += v4.x*v4.x + v4.y*v4.y + v4.z*v4.z + v4.w*v4.w;
        }
        sum += __shfl_xor(sum, 1); sum += __shfl_xor(sum, 2);
        sum += __shfl_xor(sum, 4); sum += __shfl_xor(sum, 8);
        ssq += __shfl_xor(ssq, 1); ssq += __shfl_xor(ssq, 2);
        ssq += __shfl_xor(ssq, 4); ssq += __shfl_xor(ssq, 8);
        const float mean = sum * (1.f / D_);
        const float var  = ssq * (1.f / D_) - mean * mean;
        const float rstd = rsqrtf(var + 1e-5f);
        if (tl < S_) {
            #pragma unroll
            for (int jv = 0; jv < 3; ++jv) {
                us4 o4;
                #pragma unroll
                for (int j = 0; j < 4; ++j) {
                    int col = t16 * 12 + jv * 4 + j;
                    o4[j] = f2bf((vals[jv*4+j] - mean) * rstd * g1[col] + be1[col]);
                }
                *(us4*)&hb[(size_t)tl * D_ + t16 * 12 + jv * 4] = o4;
            }
        }
    }
}

// ---------------------------------------------------------------------------
// Fused FF (round-5 schedule, widened): gelu(x@W1+b1)@W2+b2 + resid + LN.
// 128 tok/block, 1024 threads (16 waves = 4/SIMD). Weight tiles (exact LDS
// images) double-buffered via global_load_lds; one barrier per tile.
// ---------------------------------------------------------------------------
__global__ __launch_bounds__(1024) void ff_mfma(
    us_t* __restrict__ hio,
    const us_t* __restrict__ W1T, const float* __restrict__ b1,
    const us_t* __restrict__ W2T, const float* __restrict__ b2,
    const float* __restrict__ gamma, const float* __restrict__ beta)
{
    __shared__ __align__(16) char smem[157696];
    us_t* Xs  = (us_t*)smem;               // [128][200] 51200
    us_t* Ts  = (us_t*)(smem + 51200);     // [128][200] 51200
    us_t* Wsb = (us_t*)(smem + 102400);    // [2][192][72] dbuf 55296 (2x27648!)
    float* eL = (float*)(smem + 51200);    // overlays Ts (epilogue)

    const int tid = threadIdx.x;
    const int lane = tid & 63, wid = tid >> 6;   // 16 waves
    const int g = lane >> 4, c = lane & 15;
    const int wr = wid >> 2, wc = wid & 3;       // 4x32-row, 4x48-col
    const int row0 = blockIdx.x * 128;

    // tile t = cb*6 + ph*3 + pc; src image 13824 us_t each
    auto stageW = [&](int t) {
        const int cb2 = t / 6, ph = (t % 6) / 3, pc2 = t % 3;
        const us_t* src = (ph ? W2T : W1T) + (size_t)(cb2 * 3 + pc2) * 13824;
        us_t* dst = Wsb + (size_t)(t & 1) * 13824;
        for (int i = wid; i < 27; i += 16)
            gld16(src + i * 512 + lane * 8, dst + i * 512);
    };

    for (int e = tid; e < 3072; e += 1024) {
        int tok = e / 24, v = e % 24;
        *(us8*)&Xs[tok * 200 + v * 8] = *(const us8*)&hio[(size_t)(row0 + tok) * D_ + v * 8];
    }
    stageW(0);
    __syncthreads();

    f4 acc2[2][3];
    ZACC(acc2, 2, 3);
    for (int cb = 0; cb < 4; ++cb) {
        f4 acc1[2][3];
        ZACC(acc1, 2, 3);
        #pragma unroll
        for (int pc = 0; pc < 3; ++pc) {            // FF1
            const int t = cb * 6 + pc;
            if (t < 23) stageW(t + 1);
            const us_t* W = Wsb + (size_t)(t & 1) * 13824;
            #pragma unroll
            for (int kk = 0; kk < 2; ++kk) {
                const int ka = pc * 64 + kk * 32 + g * 8;
                const int kw = kk * 32 + g * 8;
                sh8 a0 = *(const sh8*)&Xs[(32 * wr + c) * 200 + ka];
                sh8 a1 = *(const sh8*)&Xs[(32 * wr + 16 + c) * 200 + ka];
                #pragma unroll
                for (int ni = 0; ni < 3; ++ni) {
                    sh8 bf = *(const sh8*)&W[(48 * wc + 16 * ni + c) * 72 + kw];
                    acc1[0][ni] = MFMA(a0, bf, acc1[0][ni]);
                    acc1[1][ni] = MFMA(a1, bf, acc1[1][ni]);
                }
            }
            if (pc == 2) {
                #pragma unroll
                for (int ni = 0; ni < 3; ++ni) {
                    const int col = 48 * wc + 16 * ni + c;
                    const float b1v = b1[cb * 192 + col];
                    #pragma unroll
                    for (int mi = 0; mi < 2; ++mi)
                        #pragma unroll
                        for (int r = 0; r < 4; ++r) {
                            int tok = 32 * wr + 16 * mi + 4 * g + r;
                            Ts[tok * 200 + col] = f2bf(gelu_f(acc1[mi][ni][r] + b1v));
                        }
                }
            }
            __syncthreads();
        }
        #pragma unroll
        for (int pc = 0; pc < 3; ++pc) {            // FF2 partial
            const int t = cb * 6 + 3 + pc;
            if (t < 23) stageW(t + 1);
            const us_t* W = Wsb + (size_t)(t & 1) * 13824;
            #pragma unroll
            for (int kk = 0; kk < 2; ++kk) {
                const int ka = pc * 64 + kk * 32 + g * 8;
                const int kw = kk * 32 + g * 8;
                sh8 a0 = *(const sh8*)&Ts[(32 * wr + c) * 200 + ka];
                sh8 a1 = *(const sh8*)&Ts[(32 * wr + 16 + c) * 200 + ka];
                #pragma unroll
                for (int ni = 0; ni < 3; ++ni) {
                    sh8 bf = *(const sh8*)&W[(48 * wc + 16 * ni + c) * 72 + kw];
                    acc2[0][ni] = MFMA(a0, bf, acc2[0][ni]);
                    acc2[1][ni] = MFMA(a1, bf, acc2[1][ni]);
                }
            }
            __syncthreads();
        }
    }

    // epilogue in two 64-token passes (eL overlays Ts)
    for (int p = 0; p < 2; ++p) {
        if (p) __syncthreads();
        if ((wr >> 1) == p) {
            #pragma unroll
            for (int ni = 0; ni < 3; ++ni) {
                const int col = 48 * wc + 16 * ni + c;
                const float b2v = b2[col];
                #pragma unroll
                for (int mi = 0; mi < 2; ++mi)
                    #pragma unroll
                    for (int r = 0; r < 4; ++r) {
                        int tok = 32 * wr + 16 * mi + 4 * g + r;
                        eL[(tok - 64 * p) * 200 + col] =
                            acc2[mi][ni][r] + b2v + bf2f(Xs[tok * 200 + col]);
                    }
            }
        }
        __syncthreads();
        {
            const int tl = tid >> 4, t16 = tid & 15;   // 64 rows x 16 lanes
            float vals[12], sum = 0.f, ssq = 0.f;
            #pragma unroll
            for (int jv = 0; jv < 3; ++jv) {
                float4 v4 = *(const float4*)&eL[tl * 200 + t16 * 12 + jv * 4];
                vals[jv*4+0] = v4.x; vals[jv*4+1] = v4.y;
                vals[jv*4+2] = v4.z; vals[jv*4+3] = v4.w;
                sum += v4.x + v4.y + v4.z + v4.w;
                ssq += v4.x*v4.x + v4.y*v4.y + v4.z*v4.z + v4.w*v4.w;
            }
            sum += __shfl_xor(sum, 1); sum += __shfl_xor(sum, 2);
            sum += __shfl_xor(sum, 4); sum += __shfl_xor(sum, 8);
            ssq += __shfl_xor(ssq, 1); ssq += __shfl_xor(ssq, 2);
            ssq += __shfl_xor(ssq, 4); ssq += __shfl_xor(ssq, 8);
            const float mean = sum * (1.f / D_);
            const float var  = ssq * (1.f / D_) - mean * mean;
            const float rstd = rsqrtf(var + 1e-5f);
            #pragma unroll
            for (int jv = 0; jv < 3; ++jv) {
                us4 o4;
                #pragma unroll
                for (int j = 0; j < 4; ++j) {
                    int col = t16 * 12 + jv * 4 + j;
                    o4[j] = f2bf((vals[jv*4+j] - mean) * rstd * gamma[col] + beta[col]);
                }
                *(us4*)&hio[(size_t)(row0 + 64 * p + tl) * D_ + t16 * 12 + jv * 4] = o4;
            }
        }
    }
}

// ---------------------------------------------------------------------------
// Classifier stage 1 (MFMA): hid = bf16(gelu(h @ Wc1 + bc1)). 64 tok/block.
// ---------------------------------------------------------------------------
__global__ __launch_bounds__(256) void clf1_mfma(
    const us_t* __restrict__ h, const us_t* __restrict__ Wc1t,
    const float* __restrict__ bc1, us_t* __restrict__ hid)
{
    __shared__ __align__(16) char smem[25600 + 13824];
    us_t* Xs = (us_t*)smem;              // [64][200]
    us_t* Ws = (us_t*)(smem + 25600);    // [96][72]
    const int tid = threadIdx.x;
    const int lane = tid & 63, wid = tid >> 6;
    const int g = lane >> 4, c = lane & 15;
    const int wr = wid >> 1, wc = wid & 1;
    const int row0 = blockIdx.x * 64;

    for (int e = tid; e < 1536; e += 256) {
        int tok = e / 24, v = e % 24;
        *(us8*)&Xs[tok * 200 + v * 8] = *(const us8*)&h[(size_t)(row0 + tok) * D_ + v * 8];
    }
    f4 acc[2][3];
    ZACC(acc, 2, 3);
    for (int pc = 0; pc < 3; ++pc) {
        __syncthreads();
        for (int e = tid; e < 768; e += 256) {
            int rw = e >> 3, v = e & 7;
            *(us8*)&Ws[rw * 72 + v * 8] =
                *(const us8*)&Wc1t[(size_t)rw * 192 + pc * 64 + v * 8];
        }
        __syncthreads();
        #pragma unroll
        for (int kk = 0; kk < 2; ++kk) {
            const int ka = pc * 64 + kk * 32 + g * 8;
            const int kw = kk * 32 + g * 8;
            sh8 a0 = *(const sh8*)&Xs[(32 * wr + c) * 200 + ka];
            sh8 a1 = *(const sh8*)&Xs[(32 * wr + 16 + c) * 200 + ka];
            #pragma unroll
            for (int ni = 0; ni < 3; ++ni) {
                sh8 bf = *(const sh8*)&Ws[(48 * wc + 16 * ni + c) * 72 + kw];
                acc[0][ni] = MFMA(a0, bf, acc[0][ni]);
                acc[1][ni] = MFMA(a1, bf, acc[1][ni]);
            }
        }
    }
    #pragma unroll
    for (int ni = 0; ni < 3; ++ni) {
        const int col = 48 * wc + 16 * ni + c;
        const float bv = bc1[col];
        #pragma unroll
        for (int mi = 0; mi < 2; ++mi)
            #pragma unroll
            for (int r = 0; r < 4; ++r) {
                int tok = row0 + 32 * wr + 16 * mi + 4 * g + r;
                hid[(size_t)tok * DH_ + col] = f2bf(gelu_f(acc[mi][ni][r] + bv));
            }
    }
}

// ---------------------------------------------------------------------------
// Classifier stage 2: out = hid @ Wc2 + bc2 (f32 VALU, tiny)
// ---------------------------------------------------------------------------
__global__ __launch_bounds__(256) void clf2_kernel(
    const us_t* __restrict__ hid, const float* __restrict__ Wc2,
    const float* __restrict__ bc2, float* __restrict__ out)
{
    __shared__ us_t Hs[64 * 104];
    __shared__ float Wl[DH_ * NC_];
    __shared__ float bl[NC_];
    const int tid = threadIdx.x;
    const int row0 = blockIdx.x * 64;
    for (int e = tid; e < 768; e += 256) {
        int tok = e / 12, v = e % 12;
        *(us8*)&Hs[tok * 104 + v * 8] = *(const us8*)&hid[(size_t)(row0 + tok) * DH_ + v * 8];
    }
    for (int e = tid; e < DH_ * NC_; e += 256) Wl[e] = Wc2[e];
    if (tid < NC_) bl[tid] = bc2[tid];
    __syncthreads();
    for (int e = tid; e < 64 * NC_; e += 256) {
        const int tok = e / NC_, col = e % NC_;
        float acc = bl[col];
        #pragma unroll 8
        for (int kk = 0; kk < DH_; ++kk)
            acc = fmaf(bf2f(Hs[tok * 104 + kk]), Wl[kk * NC_ + col], acc);
        out[(size_t)(row0 + tok) * NC_ + col] = acc;
    }
}

extern "C" void kernel_launch(void* const* d_in, const int* in_sizes, int n_in,
                              void* d_out, int out_size, void* d_ws, size_t ws_size,
                              hipStream_t stream)
{
    const float* x    = (const float*)d_in[0];
    const float* W_in = (const float*)d_in[1];
    const float* b_in = (const float*)d_in[2];
    const float* pe   = (const float*)d_in[3];
    const float* Wq   = (const float*)d_in[4];
    const float* bq   = (const float*)d_in[5];
    const float* Wk   = (const float*)d_in[6];
    const float* bk   = (const float*)d_in[7];
    const float* Wv   = (const float*)d_in[8];
    const float* bv   = (const float*)d_in[9];
    const float* Wo   = (const float*)d_in[10];
    const float* bo   = (const float*)d_in[11];
    const float* W1   = (const float*)d_in[12];
    const float* b1   = (const float*)d_in[13];
    const float* W2   = (const float*)d_in[14];
    const float* b2   = (const float*)d_in[15];
    const float* g1   = (const float*)d_in[16];
    const float* be1  = (const float*)d_in[17];
    const float* g2   = (const float*)d_in[18];
    const float* be2  = (const float*)d_in[19];
    const float* Wc1  = (const float*)d_in[20];
    const float* bc1  = (const float*)d_in[21];
    const float* Wc2  = (const float*)d_in[22];
    const float* bc2  = (const float*)d_in[23];
    float* outp = (float*)d_out;

    // ws layout (us_t elems): h | hid | Wint | Wq/k/v/ot | W1T | W2T | Wc1t
    us_t* h    = (us_t*)d_ws;
    us_t* hid  = h + (size_t)NTOK * D_;
    us_t* Wint = hid + (size_t)NTOK * DH_;
    us_t* Wqt  = Wint + 192 * 224;
    us_t* Wkt  = Wqt + 3 * 36864;
    us_t* Wvt  = Wkt + 3 * 36864;
    us_t* Wot  = Wvt + 3 * 36864;
    us_t* W1T  = Wot + 3 * 36864;
    us_t* W2T  = W1T + (size_t)L_ * 12 * 13824;
    us_t* Wc1t = W2T + (size_t)L_ * 12 * 13824;

    // ---- weight prep ----
    prep_t<<<168, 256, 0, stream>>>(W_in, Wint, IND_, 224, D_);
    for (int l = 0; l < L_; ++l) {
        prep_t<<<144, 256, 0, stream>>>(Wq + (size_t)l * 36864, Wqt + (size_t)l * 36864, 192, 192, 192);
        prep_t<<<144, 256, 0, stream>>>(Wk + (size_t)l * 36864, Wkt + (size_t)l * 36864, 192, 192, 192);
        prep_t<<<144, 256, 0, stream>>>(Wv + (size_t)l * 36864, Wvt + (size_t)l * 36864, 192, 192, 192);
        prep_t<<<144, 256, 0, stream>>>(Wo + (size_t)l * 36864, Wot + (size_t)l * 36864, 192, 192, 192);
    }
    prep_ff<<<(L_ * 12 * 13824 + 255) / 256, 256, 0, stream>>>(W1, W2, W1T, W2T);
    prep_t<<<72, 256, 0, stream>>>(Wc1, Wc1t, 192, 192, DH_);

    // ---- forward ----
    inp_mfma<<<NTOK / 64, 256, 0, stream>>>(x, Wint, b_in, pe, h);

    for (int l = 0; l < L_; ++l) {
        qkv_attn_wo<<<B_, 1024, 0, stream>>>(
            h,
            Wqt + (size_t)l * 36864, Wkt + (size_t)l * 36864,
            Wvt + (size_t)l * 36864, Wot + (size_t)l * 36864,
            bq + l * D_, bk + l * D_, bv + l * D_, bo + l * D_,
            g1 + l * D_, be1 + l * D_);
        ff_mfma<<<NTOK / 128, 1024, 0, stream>>>(
            h, W1T + (size_t)l * 12 * 13824, b1 + l * DFF_,
            W2T + (size_t)l * 12 * 13824, b2 + l * D_,
            g2 + l * D_, be2 + l * D_);
    }

    clf1_mfma<<<NTOK / 64, 256, 0, stream>>>(h, Wc1t, bc1, hid);
    clf2_kernel<<<NTOK / 64, 256, 0, stream>>>(hid, Wc2, bc2, outp);
}

// Round 12
// 1108.878 us; speedup vs baseline: 1.4006x; 1.0641x over previous
//
#include <hip/hip_runtime.h>
#include <cmath>

#define B_   2048
#define S_   60
#define NTOK (B_*S_)
#define IND_ 211
#define D_   192
#define H_   6
#define DK_  32
#define L_   3
#define DFF_ 768
#define NC_  35
#define DH_  96

typedef unsigned short us_t;
typedef us_t us8 __attribute__((ext_vector_type(8)));
typedef us_t us4 __attribute__((ext_vector_type(4)));
typedef short sh8 __attribute__((ext_vector_type(8)));
typedef float f4 __attribute__((ext_vector_type(4)));

#define MFMA(a, b, cc) __builtin_amdgcn_mfma_f32_16x16x32_bf16((a), (b), (cc), 0, 0, 0)
#define ZACC(A, M, N) \
    for (int _i = 0; _i < (M); ++_i) \
        for (int _j = 0; _j < (N); ++_j) { \
            A[_i][_j][0] = 0.f; A[_i][_j][1] = 0.f; A[_i][_j][2] = 0.f; A[_i][_j][3] = 0.f; }
#define ZACC1(A, N) \
    for (int _j = 0; _j < (N); ++_j) { \
        A[_j][0] = 0.f; A[_j][1] = 0.f; A[_j][2] = 0.f; A[_j][3] = 0.f; }

__device__ __forceinline__ float bf2f(us_t u) {
    union { unsigned int i; float f; } v; v.i = ((unsigned int)u) << 16; return v.f;
}
__device__ __forceinline__ us_t f2bf(float f) {
    union { float f; unsigned int i; } v; v.f = f;
    unsigned int r = v.i + 0x7fffu + ((v.i >> 16) & 1u);
    return (us_t)(r >> 16);
}
// fast tanh-gelu: |err| < 1e-3 vs exact erf-gelu, well under bf16 rounding
__device__ __forceinline__ float gelu_f(float v) {
    float u = v * (0.7978845608f + 0.0356774081f * v * v);
    float e = __expf(2.f * u);
    float t = 1.f - 2.f / (e + 1.f);       // overflow-safe tanh
    return 0.5f * v * (1.f + t);
}
__device__ __forceinline__ void gld16(const us_t* g, us_t* s) {
    __builtin_amdgcn_global_load_lds(
        (const __attribute__((address_space(1))) unsigned int*)(g),
        (__attribute__((address_space(3))) unsigned int*)(s), 16, 0, 0);
}

// ---------------------------------------------------------------------------
// prep_misc: Wint [192][224] + Wc1t [96][192] transposed bf16 images.
// ---------------------------------------------------------------------------
__global__ void prep_misc(const float* __restrict__ W_in, const float* __restrict__ Wc1,
                          us_t* __restrict__ Wint, us_t* __restrict__ Wc1t)
{
    int e = blockIdx.x * 256 + threadIdx.x;
    const int n1 = 192 * 224, n2 = 96 * 192;
    if (e < n1) {
        int n = e / 224, kp = e % 224;
        Wint[e] = (kp < IND_) ? f2bf(W_in[(size_t)kp * D_ + n]) : (us_t)0;
    } else if (e < n1 + n2) {
        int r = e - n1;
        int n = r / 192, kp = r % 192;
        Wc1t[r] = f2bf(Wc1[(size_t)kp * DH_ + n]);
    }
}

// ---------------------------------------------------------------------------
// prep_qkvw: per layer 12 images [192][72] (13824 us_t):
// t<9: mat=t/3 (q,k,v), pc=t%3;  t>=9: Wo, pc=t-9.
// image[rw*72+kk] = Wmat[l][(pc*64+kk)*192 + rw], kk>=64 -> 0.
// ---------------------------------------------------------------------------
__global__ void prep_qkvw(const float* __restrict__ Wq, const float* __restrict__ Wk,
                          const float* __restrict__ Wv, const float* __restrict__ Wo,
                          us_t* __restrict__ WI)
{
    int e = blockIdx.x * 256 + threadIdx.x;
    if (e >= L_ * 12 * 13824) return;
    int l = e / (12 * 13824), r = e % (12 * 13824);
    int t = r / 13824, q = r % 13824;
    int rw = q / 72, kk = q % 72;
    us_t v = 0;
    if (kk < 64) {
        int mat = (t < 9) ? (t / 3) : 3;
        int pc  = (t < 9) ? (t % 3) : (t - 9);
        const float* W = (mat == 0) ? Wq : (mat == 1) ? Wk : (mat == 2) ? Wv : Wo;
        v = f2bf(W[(size_t)l * 36864 + (size_t)(pc * 64 + kk) * D_ + rw]);
    }
    WI[e] = v;
}

// ---------------------------------------------------------------------------
// FF weight prep: tile-contiguous LDS images. Per layer 12 tiles x [192][72].
// ---------------------------------------------------------------------------
__global__ void prep_ff(const float* __restrict__ W1, const float* __restrict__ W2,
                        us_t* __restrict__ W1T, us_t* __restrict__ W2T)
{
    int e = blockIdx.x * 256 + threadIdx.x;
    if (e >= L_ * 12 * 13824) return;
    int l = e / (12 * 13824), r = e % (12 * 13824);
    int tile = r / 13824, q = r % 13824;
    int col = q / 72, kk = q % 72;
    int cb = tile / 3, pc = tile % 3;
    us_t v1 = 0, v2 = 0;
    if (kk < 64) {
        v1 = f2bf(W1[((size_t)l * D_ + pc * 64 + kk) * DFF_ + cb * D_ + col]);
        v2 = f2bf(W2[((size_t)l * DFF_ + cb * D_ + pc * 64 + kk) * D_ + col]);
    }
    W1T[e] = v1; W2T[e] = v2;
}

// ---------------------------------------------------------------------------
// Input projection: h = bf16(x @ W_in + b_in + pe). 64 tok/block, 4 waves.
// ---------------------------------------------------------------------------
__global__ __launch_bounds__(256) void inp_mfma(
    const float* __restrict__ x, const us_t* __restrict__ Wint,
    const float* __restrict__ b_in, const float* __restrict__ pe,
    us_t* __restrict__ h)
{
    __shared__ __align__(16) char smem[29696 + 27648];
    us_t* Xs = (us_t*)smem;              // [64][232]
    us_t* Ws = (us_t*)(smem + 29696);    // [192][72]
    const int tid = threadIdx.x;
    const int lane = tid & 63, wid = tid >> 6;
    const int g = lane >> 4, c = lane & 15;
    const int wr = wid >> 1, wc = wid & 1;
    const int row0 = blockIdx.x * 64;

    for (int e = tid; e < 64 * 224; e += 256) {
        int tok = e / 224, kp = e % 224;
        float v = (kp < IND_) ? x[(size_t)(row0 + tok) * IND_ + kp] : 0.f;
        Xs[tok * 232 + kp] = f2bf(v);
    }

    f4 acc[2][6];
    ZACC(acc, 2, 6);
    for (int pc = 0; pc < 4; ++pc) {
        __syncthreads();
        const int nk = (pc < 3) ? 64 : 32;
        const int per = nk / 8;
        for (int e = tid; e < 192 * per; e += 256) {
            int rw = e / per, v = e % per;
            *(us8*)&Ws[rw * 72 + v * 8] =
                *(const us8*)&Wint[(size_t)rw * 224 + pc * 64 + v * 8];
        }
        __syncthreads();
        for (int kk = 0; kk < nk / 32; ++kk) {
            const int ka = pc * 64 + kk * 32 + g * 8;
            const int kw = kk * 32 + g * 8;
            sh8 a0 = *(const sh8*)&Xs[(32 * wr + c) * 232 + ka];
            sh8 a1 = *(const sh8*)&Xs[(32 * wr + 16 + c) * 232 + ka];
            #pragma unroll
            for (int ni = 0; ni < 6; ++ni) {
                sh8 bf = *(const sh8*)&Ws[(96 * wc + 16 * ni + c) * 72 + kw];
                acc[0][ni] = MFMA(a0, bf, acc[0][ni]);
                acc[1][ni] = MFMA(a1, bf, acc[1][ni]);
            }
        }
    }
    #pragma unroll
    for (int ni = 0; ni < 6; ++ni) {
        const int col = 96 * wc + 16 * ni + c;
        const float bv = b_in[col];
        #pragma unroll
        for (int mi = 0; mi < 2; ++mi)
            #pragma unroll
            for (int r = 0; r < 4; ++r) {
                int tokg = row0 + 32 * wr + 16 * mi + 4 * g + r;
                int s = tokg % S_;
                float val = acc[mi][ni][r] + bv + pe[(size_t)s * D_ + col];
                h[(size_t)tokg * D_ + col] = f2bf(val);
            }
    }
}

// ---------------------------------------------------------------------------
// Fused QKV + attention + Wo + residual + LN. 1024 threads (16 waves).
// Weight stages via gld16 double-buffer (12 pre-tiled images/layer), one
// barrier per stage. all-scores -> all-PV; P[6] overlays the weight dbuf,
// ctx overlays dead Qs. LDS 156 KB.
// ---------------------------------------------------------------------------
__global__ __launch_bounds__(1024) void qkv_attn_wo(
    us_t* __restrict__ h, const us_t* __restrict__ WI,
    const float* __restrict__ bq, const float* __restrict__ bk,
    const float* __restrict__ bv, const float* __restrict__ bo,
    const float* __restrict__ g1, const float* __restrict__ be1)
{
    __shared__ __align__(16) char smem[159744];
    us_t* Xs  = (us_t*)smem;               // [64][200] 25600
    us_t* Qs  = (us_t*)(smem + 25600);     // [64][200]
    us_t* Ks  = (us_t*)(smem + 51200);     // [64][200]
    us_t* Vt  = (us_t*)(smem + 76800);     // [192][72] 27648
    us_t* Wsb = (us_t*)(smem + 104448);    // [2][13824] dbuf 55296
    us_t* P6  = (us_t*)(smem + 104448);    // [6][64][72] overlays Wsb
    us_t* Cx  = (us_t*)(smem + 25600);     // overlays Qs (dead after scores)
    float* eL = (float*)(smem + 51200);    // [64][200] f32 over Ks+Vt

    const int tid = threadIdx.x;
    const int lane = tid & 63, wid = tid >> 6;   // 16 waves
    const int g = lane >> 4, c = lane & 15;
    const int wr = wid >> 2, wc = wid & 3;       // 4x16-row, 4x48-col
    us_t* hb = h + (size_t)blockIdx.x * (S_ * D_);

    auto stageI = [&](int t) {
        const us_t* src = WI + (size_t)t * 13824;
        us_t* dst = Wsb + (size_t)(t & 1) * 13824;
        for (int i = wid; i < 27; i += 16)
            gld16(src + i * 512 + lane * 8, dst + i * 512);
    };

    // prologue: X staging (rows 60..63 zero) + first weight image
    for (int e = tid; e < 1536; e += 1024) {
        int tok = e / 24, v = e % 24;
        us8 u = {0, 0, 0, 0, 0, 0, 0, 0};
        if (tok < S_) u = *(const us8*)&hb[(size_t)tok * D_ + v * 8];
        *(us8*)&Xs[tok * 200 + v * 8] = u;
    }
    stageI(0);
    __syncthreads();

    // ---- QKV projections (images t=0..8) ----
    for (int m = 0; m < 3; ++m) {
        const float* bb = (m == 0) ? bq : (m == 1) ? bk : bv;
        f4 acc[3];
        ZACC1(acc, 3);
        for (int pc = 0; pc < 3; ++pc) {
            const int t = m * 3 + pc;
            if (t < 8) stageI(t + 1);
            const us_t* W = Wsb + (size_t)(t & 1) * 13824;
            #pragma unroll
            for (int kk = 0; kk < 2; ++kk) {
                const int ka = pc * 64 + kk * 32 + g * 8;
                const int kw = kk * 32 + g * 8;
                sh8 a0 = *(const sh8*)&Xs[(16 * wr + c) * 200 + ka];
                #pragma unroll
                for (int ni = 0; ni < 3; ++ni) {
                    sh8 bf = *(const sh8*)&W[(48 * wc + 16 * ni + c) * 72 + kw];
                    acc[ni] = MFMA(a0, bf, acc[ni]);
                }
            }
            __syncthreads();
        }
        #pragma unroll
        for (int ni = 0; ni < 3; ++ni) {
            const int col = 48 * wc + 16 * ni + c;
            const float bval = bb[col];
            #pragma unroll
            for (int r = 0; r < 4; ++r) {
                int tok = 16 * wr + 4 * g + r;
                us_t o = f2bf(acc[ni][r] + bval);
                if (m == 0)      Qs[tok * 200 + col] = o;
                else if (m == 1) Ks[tok * 200 + col] = o;
                else             Vt[col * 72 + tok] = o;
            }
        }
    }
    __syncthreads();   // Q/K/V visible; weight dbuf now free -> P6

    // ---- scores + softmax for ALL 6 heads (writes P6) ----
    for (int r2 = 0; r2 < 2; ++r2) {
        if (wid < 12) {
            const int hh = 3 * r2 + (wid >> 2);
            const int hgrp = wid & 3;
            us_t* Pb = P6 + (size_t)hh * 4608;
            f4 sc[4];
            ZACC1(sc, 4);
            const int ka = 32 * hh + g * 8;
            sh8 aq = *(const sh8*)&Qs[(16 * hgrp + c) * 200 + ka];
            #pragma unroll
            for (int ni = 0; ni < 4; ++ni) {
                sh8 bk8 = *(const sh8*)&Ks[(16 * ni + c) * 200 + ka];
                sc[ni] = MFMA(aq, bk8, sc[ni]);
            }
            #pragma unroll
            for (int r = 0; r < 4; ++r) {
                float mx = -1e30f;
                #pragma unroll
                for (int ni = 0; ni < 4; ++ni) {
                    float v = sc[ni][r] * 0.17677669529663687f;
                    if (16 * ni + c >= S_) v = -1e30f;
                    sc[ni][r] = v;
                    mx = fmaxf(mx, v);
                }
                mx = fmaxf(mx, __shfl_xor(mx, 1));
                mx = fmaxf(mx, __shfl_xor(mx, 2));
                mx = fmaxf(mx, __shfl_xor(mx, 4));
                mx = fmaxf(mx, __shfl_xor(mx, 8));
                float sum = 0.f;
                #pragma unroll
                for (int ni = 0; ni < 4; ++ni) {
                    float e = __expf(sc[ni][r] - mx);
                    sc[ni][r] = e; sum += e;
                }
                sum += __shfl_xor(sum, 1);
                sum += __shfl_xor(sum, 2);
                sum += __shfl_xor(sum, 4);
                sum += __shfl_xor(sum, 8);
                const float inv = 1.f / sum;
                #pragma unroll
                for (int ni = 0; ni < 4; ++ni)
                    Pb[(16 * hgrp + 4 * g + r) * 72 + 16 * ni + c] = f2bf(sc[ni][r] * inv);
            }
        }
    }
    __syncthreads();   // P6 visible; Qs dead -> Cx

    // ---- PV for all 6 heads (writes Cx) ----
    for (int r2 = 0; r2 < 2; ++r2) {
        if (wid < 12) {
            const int hh = 3 * r2 + (wid >> 2);
            const int hgrp = wid & 3;
            const us_t* Pb = P6 + (size_t)hh * 4608;
            f4 ov[2];
            ZACC1(ov, 2);
            #pragma unroll
            for (int kk = 0; kk < 2; ++kk) {
                sh8 ap = *(const sh8*)&Pb[(16 * hgrp + c) * 72 + kk * 32 + g * 8];
                #pragma unroll
                for (int n2 = 0; n2 < 2; ++n2) {
                    sh8 bv8 = *(const sh8*)&Vt[(32 * hh + 16 * n2 + c) * 72 + kk * 32 + g * 8];
                    ov[n2] = MFMA(ap, bv8, ov[n2]);
                }
            }
            #pragma unroll
            for (int n2 = 0; n2 < 2; ++n2)
                #pragma unroll
                for (int r = 0; r < 4; ++r)
                    Cx[(16 * hgrp + 4 * g + r) * 200 + 32 * hh + 16 * n2 + c] = f2bf(ov[n2][r]);
        }
    }
    __syncthreads();   // Cx visible; P6 dead -> weight dbuf again

    // ---- Wo (images t=9..11) ----
    stageI(9);
    __syncthreads();
    f4 aw[3];
    ZACC1(aw, 3);
    for (int pc = 0; pc < 3; ++pc) {
        const int t = 9 + pc;
        if (pc < 2) stageI(t + 1);
        const us_t* W = Wsb + (size_t)(t & 1) * 13824;
        #pragma unroll
        for (int kk = 0; kk < 2; ++kk) {
            const int ka = pc * 64 + kk * 32 + g * 8;
            const int kw = kk * 32 + g * 8;
            sh8 a0 = *(const sh8*)&Cx[(16 * wr + c) * 200 + ka];
            #pragma unroll
            for (int ni = 0; ni < 3; ++ni) {
                sh8 bf = *(const sh8*)&W[(48 * wc + 16 * ni + c) * 72 + kw];
                aw[ni] = MFMA(a0, bf, aw[ni]);
            }
        }
        __syncthreads();
    }
    // residual add into eL (Ks/Vt dead)
    #pragma unroll
    for (int ni = 0; ni < 3; ++ni) {
        const int col = 48 * wc + 16 * ni + c;
        const float bov = bo[col];
        #pragma unroll
        for (int r = 0; r < 4; ++r) {
            int tok = 16 * wr + 4 * g + r;
            eL[tok * 200 + col] = aw[ni][r] + bov + bf2f(Xs[tok * 200 + col]);
        }
    }
    __syncthreads();
    // LayerNorm: 64 rows x 16 lanes, 12 cols each
    {
        const int tl = tid >> 4, t16 = tid & 15;
        float vals[12], sum = 0.f, ssq = 0.f;
        #pragma unroll
        for (int jv = 0; jv < 3; ++jv) {
            float4 v4 = *(const float4*)&eL[tl * 200 + t16 * 12 + jv * 4];
            vals[jv*4+0] = v4.x; vals[jv*4+1] = v4.y; vals[jv*4+2] = v4.z; vals[jv*4+3] = v4.w;
            sum += v4.x + v4.y + v4.z + v4.w;
            ssq += v4.x*v4.x + v4.y*v4.y + v4.z*v4.z + v4.w*v4.w;
        }
        sum += __shfl_xor(sum, 1); sum += __shfl_xor(sum, 2);
        sum += __shfl_xor(sum, 4); sum += __shfl_xor(sum, 8);
        ssq += __shfl_xor(ssq, 1); ssq += __shfl_xor(ssq, 2);
        ssq += __shfl_xor(ssq, 4); ssq += __shfl_xor(ssq, 8);
        const float mean = sum * (1.f / D_);
        const float var  = ssq * (1.f / D_) - mean * mean;
        const float rstd = rsqrtf(var + 1e-5f);
        if (tl < S_) {
            #pragma unroll
            for (int jv = 0; jv < 3; ++jv) {
                us4 o4;
                #pragma unroll
                for (int j = 0; j < 4; ++j) {
                    int col = t16 * 12 + jv * 4 + j;
                    o4[j] = f2bf((vals[jv*4+j] - mean) * rstd * g1[col] + be1[col]);
                }
                *(us4*)&hb[(size_t)tl * D_ + t16 * 12 + jv * 4] = o4;
            }
        }
    }
}

// ---------------------------------------------------------------------------
// Fused FF (round-11, unchanged): 128 tok/block, 1024 threads.
// ---------------------------------------------------------------------------
__global__ __launch_bounds__(1024) void ff_mfma(
    us_t* __restrict__ hio,
    const us_t* __restrict__ W1T, const float* __restrict__ b1,
    const us_t* __restrict__ W2T, const float* __restrict__ b2,
    const float* __restrict__ gamma, const float* __restrict__ beta)
{
    __shared__ __align__(16) char smem[157696];
    us_t* Xs  = (us_t*)smem;               // [128][200] 51200
    us_t* Ts  = (us_t*)(smem + 51200);     // [128][200] 51200
    us_t* Wsb = (us_t*)(smem + 102400);    // [2][192][72] dbuf 55296
    float* eL = (float*)(smem + 51200);    // overlays Ts (epilogue)

    const int tid = threadIdx.x;
    const int lane = tid & 63, wid = tid >> 6;   // 16 waves
    const int g = lane >> 4, c = lane & 15;
    const int wr = wid >> 2, wc = wid & 3;       // 4x32-row, 4x48-col
    const int row0 = blockIdx.x * 128;

    auto stageW = [&](int t) {
        const int cb2 = t / 6, ph = (t % 6) / 3, pc2 = t % 3;
        const us_t* src = (ph ? W2T : W1T) + (size_t)(cb2 * 3 + pc2) * 13824;
        us_t* dst = Wsb + (size_t)(t & 1) * 13824;
        for (int i = wid; i < 27; i += 16)
            gld16(src + i * 512 + lane * 8, dst + i * 512);
    };

    for (int e = tid; e < 3072; e += 1024) {
        int tok = e / 24, v = e % 24;
        *(us8*)&Xs[tok * 200 + v * 8] = *(const us8*)&hio[(size_t)(row0 + tok) * D_ + v * 8];
    }
    stageW(0);
    __syncthreads();

    f4 acc2[2][3];
    ZACC(acc2, 2, 3);
    for (int cb = 0; cb < 4; ++cb) {
        f4 acc1[2][3];
        ZACC(acc1, 2, 3);
        #pragma unroll
        for (int pc = 0; pc < 3; ++pc) {            // FF1
            const int t = cb * 6 + pc;
            if (t < 23) stageW(t + 1);
            const us_t* W = Wsb + (size_t)(t & 1) * 13824;
            #pragma unroll
            for (int kk = 0; kk < 2; ++kk) {
                const int ka = pc * 64 + kk * 32 + g * 8;
                const int kw = kk * 32 + g * 8;
                sh8 a0 = *(const sh8*)&Xs[(32 * wr + c) * 200 + ka];
                sh8 a1 = *(const sh8*)&Xs[(32 * wr + 16 + c) * 200 + ka];
                #pragma unroll
                for (int ni = 0; ni < 3; ++ni) {
                    sh8 bf = *(const sh8*)&W[(48 * wc + 16 * ni + c) * 72 + kw];
                    acc1[0][ni] = MFMA(a0, bf, acc1[0][ni]);
                    acc1[1][ni] = MFMA(a1, bf, acc1[1][ni]);
                }
            }
            if (pc == 2) {
                #pragma unroll
                for (int ni = 0; ni < 3; ++ni) {
                    const int col = 48 * wc + 16 * ni + c;
                    const float b1v = b1[cb * 192 + col];
                    #pragma unroll
                    for (int mi = 0; mi < 2; ++mi)
                        #pragma unroll
                        for (int r = 0; r < 4; ++r) {
                            int tok = 32 * wr + 16 * mi + 4 * g + r;
                            Ts[tok * 200 + col] = f2bf(gelu_f(acc1[mi][ni][r] + b1v));
                        }
                }
            }
            __syncthreads();
        }
        #pragma unroll
        for (int pc = 0; pc < 3; ++pc) {            // FF2 partial
            const int t = cb * 6 + 3 + pc;
            if (t < 23) stageW(t + 1);
            const us_t* W = Wsb + (size_t)(t & 1) * 13824;
            #pragma unroll
            for (int kk = 0; kk < 2; ++kk) {
                const int ka = pc * 64 + kk * 32 + g * 8;
                const int kw = kk * 32 + g * 8;
                sh8 a0 = *(const sh8*)&Ts[(32 * wr + c) * 200 + ka];
                sh8 a1 = *(const sh8*)&Ts[(32 * wr + 16 + c) * 200 + ka];
                #pragma unroll
                for (int ni = 0; ni < 3; ++ni) {
                    sh8 bf = *(const sh8*)&W[(48 * wc + 16 * ni + c) * 72 + kw];
                    acc2[0][ni] = MFMA(a0, bf, acc2[0][ni]);
                    acc2[1][ni] = MFMA(a1, bf, acc2[1][ni]);
                }
            }
            __syncthreads();
        }
    }

    for (int p = 0; p < 2; ++p) {
        if (p) __syncthreads();
        if ((wr >> 1) == p) {
            #pragma unroll
            for (int ni = 0; ni < 3; ++ni) {
                const int col = 48 * wc + 16 * ni + c;
                const float b2v = b2[col];
                #pragma unroll
                for (int mi = 0; mi < 2; ++mi)
                    #pragma unroll
                    for (int r = 0; r < 4; ++r) {
                        int tok = 32 * wr + 16 * mi + 4 * g + r;
                        eL[(tok - 64 * p) * 200 + col] =
                            acc2[mi][ni][r] + b2v + bf2f(Xs[tok * 200 + col]);
                    }
            }
        }
        __syncthreads();
        {
            const int tl = tid >> 4, t16 = tid & 15;
            float vals[12], sum = 0.f, ssq = 0.f;
            #pragma unroll
            for (int jv = 0; jv < 3; ++jv) {
                float4 v4 = *(const float4*)&eL[tl * 200 + t16 * 12 + jv * 4];
                vals[jv*4+0] = v4.x; vals[jv*4+1] = v4.y;
                vals[jv*4+2] = v4.z; vals[jv*4+3] = v4.w;
                sum += v4.x + v4.y + v4.z + v4.w;
                ssq += v4.x*v4.x + v4.y*v4.y + v4.z*v4.z + v4.w*v4.w;
            }
            sum += __shfl_xor(sum, 1); sum += __shfl_xor(sum, 2);
            sum += __shfl_xor(sum, 4); sum += __shfl_xor(sum, 8);
            ssq += __shfl_xor(ssq, 1); ssq += __shfl_xor(ssq, 2);
            ssq += __shfl_xor(ssq, 4); ssq += __shfl_xor(ssq, 8);
            const float mean = sum * (1.f / D_);
            const float var  = ssq * (1.f / D_) - mean * mean;
            const float rstd = rsqrtf(var + 1e-5f);
            #pragma unroll
            for (int jv = 0; jv < 3; ++jv) {
                us4 o4;
                #pragma unroll
                for (int j = 0; j < 4; ++j) {
                    int col = t16 * 12 + jv * 4 + j;
                    o4[j] = f2bf((vals[jv*4+j] - mean) * rstd * gamma[col] + beta[col]);
                }
                *(us4*)&hio[(size_t)(row0 + 64 * p + tl) * D_ + t16 * 12 + jv * 4] = o4;
            }
        }
    }
}

// ---------------------------------------------------------------------------
// Merged classifier: out = gelu(h@Wc1+bc1) @ Wc2 + bc2. 64 tok/block.
// hid stays in LDS (never touches HBM).
// ---------------------------------------------------------------------------
__global__ __launch_bounds__(256) void clf12(
    const us_t* __restrict__ h, const us_t* __restrict__ Wc1t,
    const float* __restrict__ bc1, const float* __restrict__ Wc2,
    const float* __restrict__ bc2, float* __restrict__ out)
{
    __shared__ __align__(16) char smem[25600 + 13824 + 13312];
    us_t* Xs = (us_t*)smem;                       // [64][200]
    us_t* Ws = (us_t*)(smem + 25600);             // [96][72]
    us_t* Hs = (us_t*)(smem + 25600 + 13824);     // [64][104]
    __shared__ float Wl[DH_ * NC_];
    __shared__ float bl[NC_];
    const int tid = threadIdx.x;
    const int lane = tid & 63, wid = tid >> 6;
    const int g = lane >> 4, c = lane & 15;
    const int wr = wid >> 1, wc = wid & 1;
    const int row0 = blockIdx.x * 64;

    for (int e = tid; e < 1536; e += 256) {
        int tok = e / 24, v = e % 24;
        *(us8*)&Xs[tok * 200 + v * 8] = *(const us8*)&h[(size_t)(row0 + tok) * D_ + v * 8];
    }
    for (int e = tid; e < DH_ * NC_; e += 256) Wl[e] = Wc2[e];
    if (tid < NC_) bl[tid] = bc2[tid];

    f4 acc[2][3];
    ZACC(acc, 2, 3);
    for (int pc = 0; pc < 3; ++pc) {
        __syncthreads();
        for (int e = tid; e < 768; e += 256) {
            int rw = e >> 3, v = e & 7;
            *(us8*)&Ws[rw * 72 + v * 8] =
                *(const us8*)&Wc1t[(size_t)rw * 192 + pc * 64 + v * 8];
        }
        __syncthreads();
        #pragma unroll
        for (int kk = 0; kk < 2; ++kk) {
            const int ka = pc * 64 + kk * 32 + g * 8;
            const int kw = kk * 32 + g * 8;
            sh8 a0 = *(const sh8*)&Xs[(32 * wr + c) * 200 + ka];
            sh8 a1 = *(const sh8*)&Xs[(32 * wr + 16 + c) * 200 + ka];
            #pragma unroll
            for (int ni = 0; ni < 3; ++ni) {
                sh8 bf = *(const sh8*)&Ws[(48 * wc + 16 * ni + c) * 72 + kw];
                acc[0][ni] = MFMA(a0, bf, acc[0][ni]);
                acc[1][ni] = MFMA(a1, bf, acc[1][ni]);
            }
        }
    }
    #pragma unroll
    for (int ni = 0; ni < 3; ++ni) {
        const int col = 48 * wc + 16 * ni + c;
        const float bv = bc1[col];
        #pragma unroll
        for (int mi = 0; mi < 2; ++mi)
            #pragma unroll
            for (int r = 0; r < 4; ++r) {
                int tok = 32 * wr + 16 * mi + 4 * g + r;
                Hs[tok * 104 + col] = f2bf(gelu_f(acc[mi][ni][r] + bv));
            }
    }
    __syncthreads();
    for (int e = tid; e < 64 * NC_; e += 256) {
        const int tok = e / NC_, col = e % NC_;
        float a = bl[col];
        #pragma unroll 8
        for (int kk = 0; kk < DH_; ++kk)
            a = fmaf(bf2f(Hs[tok * 104 + kk]), Wl[kk * NC_ + col], a);
        out[(size_t)(row0 + tok) * NC_ + col] = a;
    }
}

extern "C" void kernel_launch(void* const* d_in, const int* in_sizes, int n_in,
                              void* d_out, int out_size, void* d_ws, size_t ws_size,
                              hipStream_t stream)
{
    const float* x    = (const float*)d_in[0];
    const float* W_in = (const float*)d_in[1];
    const float* b_in = (const float*)d_in[2];
    const float* pe   = (const float*)d_in[3];
    const float* Wq   = (const float*)d_in[4];
    const float* bq   = (const float*)d_in[5];
    const float* Wk   = (const float*)d_in[6];
    const float* bk   = (const float*)d_in[7];
    const float* Wv   = (const float*)d_in[8];
    const float* bv   = (const float*)d_in[9];
    const float* Wo   = (const float*)d_in[10];
    const float* bo   = (const float*)d_in[11];
    const float* W1   = (const float*)d_in[12];
    const float* b1   = (const float*)d_in[13];
    const float* W2   = (const float*)d_in[14];
    const float* b2   = (const float*)d_in[15];
    const float* g1   = (const float*)d_in[16];
    const float* be1  = (const float*)d_in[17];
    const float* g2   = (const float*)d_in[18];
    const float* be2  = (const float*)d_in[19];
    const float* Wc1  = (const float*)d_in[20];
    const float* bc1  = (const float*)d_in[21];
    const float* Wc2  = (const float*)d_in[22];
    const float* bc2  = (const float*)d_in[23];
    float* outp = (float*)d_out;

    // ws layout (us_t elems): h | Wint | WIqkv | W1T | W2T | Wc1t
    us_t* h    = (us_t*)d_ws;
    us_t* Wint = h + (size_t)NTOK * D_;
    us_t* WIq  = Wint + 192 * 224;
    us_t* W1T  = WIq + (size_t)L_ * 12 * 13824;
    us_t* W2T  = W1T + (size_t)L_ * 12 * 13824;
    us_t* Wc1t = W2T + (size_t)L_ * 12 * 13824;

    // ---- weight prep (3 launches) ----
    prep_misc<<<(192 * 224 + 96 * 192 + 255) / 256, 256, 0, stream>>>(W_in, Wc1, Wint, Wc1t);
    prep_qkvw<<<(L_ * 12 * 13824 + 255) / 256, 256, 0, stream>>>(Wq, Wk, Wv, Wo, WIq);
    prep_ff<<<(L_ * 12 * 13824 + 255) / 256, 256, 0, stream>>>(W1, W2, W1T, W2T);

    // ---- forward ----
    inp_mfma<<<NTOK / 64, 256, 0, stream>>>(x, Wint, b_in, pe, h);

    for (int l = 0; l < L_; ++l) {
        qkv_attn_wo<<<B_, 1024, 0, stream>>>(
            h, WIq + (size_t)l * 12 * 13824,
            bq + l * D_, bk + l * D_, bv + l * D_, bo + l * D_,
            g1 + l * D_, be1 + l * D_);
        ff_mfma<<<NTOK / 128, 1024, 0, stream>>>(
            h, W1T + (size_t)l * 12 * 13824, b1 + l * DFF_,
            W2T + (size_t)l * 12 * 13824, b2 + l * D_,
            g2 + l * D_, be2 + l * D_);
    }

    clf12<<<NTOK / 64, 256, 0, stream>>>(h, Wc1t, bc1, Wc2, bc2, outp);
}